// Round 1
// baseline (337.482 us; speedup 1.0000x reference)
//
#include <hip/hip_runtime.h>
#include <cstdint>
#include <cstddef>

// Problem constants (from reference)
#define B_    32
#define N_    5023
#define F_    64
#define S_    9
#define OUT_  128
#define M_TOT (B_ * N_)        // 160736 rows
#define K_    (S_ * F_)        // 576

#define BM    64               // rows per block
#define THREADS 256

// ---------------------------------------------------------------------------
// Dtype probe for spiral_adj: reference says int64, harness doc says int32.
// If the buffer is little-endian int64 with values in [0, N), every odd
// 32-bit word is 0. If int32, the odd words are random indices (essentially
// impossible that 4096 of them are all zero). Write flag: 1 = int64, 0 = int32.
// ---------------------------------------------------------------------------
__global__ void detect_idx_dtype(const int* __restrict__ adj_words,
                                 int* __restrict__ flag) {
    __shared__ int s_nz;
    if (threadIdx.x == 0) s_nz = 0;
    __syncthreads();
    int v = 0;
    for (int i = threadIdx.x; i < 4096; i += blockDim.x)
        v |= adj_words[2 * i + 1];
    if (v) atomicOr(&s_nz, 1);
    __syncthreads();
    if (threadIdx.x == 0) *flag = (s_nz == 0) ? 1 : 0;
}

__device__ __forceinline__ int load_idx(const void* adj, int is64, long long j) {
    if (is64) return (int)((const long long*)adj)[j];
    return ((const int*)adj)[j];
}

// ---------------------------------------------------------------------------
// Main kernel: per block, 64 output rows x all 128 output cols.
// K loop over s = 0..8 (each spiral slot is a contiguous 64-float chunk).
// LDS: A chunk [64 rows][64 f] (gathered), W chunk transposed [64 f][128 o].
// Thread layout: tcol = tid&31 -> 4 consecutive cols (c0 = tcol*4),
//                trow = tid>>5 -> 8 rows (r = trow*8 + i).
// ---------------------------------------------------------------------------
__global__ __launch_bounds__(THREADS, 2)
void spiral_conv_fp32(const float* __restrict__ x,
                      const void*  __restrict__ adj,
                      const float* __restrict__ W,
                      const float* __restrict__ bias,
                      float* __restrict__ out,
                      const int* __restrict__ flag) {
    __shared__ float A_lds[BM][F_];      // 16 KB
    __shared__ float Wt_lds[F_][OUT_];   // 32 KB

    const int is64 = *flag;              // wave-uniform
    const int m0   = blockIdx.x * BM;
    const int tid  = threadIdx.x;
    const int tcol = tid & 31;
    const int trow = tid >> 5;
    const int c0   = tcol * 4;

    float acc[8][4];
    {
        const float4 bv = *(const float4*)(bias + c0);
        #pragma unroll
        for (int i = 0; i < 8; ++i) {
            acc[i][0] = bv.x; acc[i][1] = bv.y; acc[i][2] = bv.z; acc[i][3] = bv.w;
        }
    }

    // A-load assignment: 4 threads per row, each loads 4 float4 (16 floats)
    const int lr = tid >> 2;             // row within tile, 0..63
    const int lq = tid & 3;              // quarter of the 64-float row
    int lm = m0 + lr;
    if (lm >= M_TOT) lm = M_TOT - 1;     // clamp (dup load, store guarded)
    const int    lb    = lm / N_;        // batch of this row
    const size_t xbase = (size_t)lb * N_ * F_;

    // W-load assignment: 2 threads per output row o, each loads 32 floats
    const int wo = tid >> 1;             // 0..127
    const int wh = tid & 1;              // half of the 64-float chunk

    for (int s = 0; s < S_; ++s) {
        // gather index + source pointer (global reads, pre-barrier)
        const int idx = load_idx(adj, is64, (long long)lm * S_ + s);
        const float4* asrc = (const float4*)(x + xbase + (size_t)idx * F_ + lq * 16);
        const float*  wsrc = W + (size_t)wo * K_ + s * F_ + wh * 32;

        __syncthreads();   // previous compute done before overwriting LDS

        {   // stage A chunk
            float4* dstA = (float4*)&A_lds[lr][lq * 16];
            dstA[0] = asrc[0]; dstA[1] = asrc[1]; dstA[2] = asrc[2]; dstA[3] = asrc[3];
        }
        {   // stage W chunk transposed: Wt[f][o] = W[o][s*64+f]
            #pragma unroll
            for (int j = 0; j < 8; ++j) {
                const float4 wv = *(const float4*)(wsrc + j * 4);
                const int f = wh * 32 + j * 4;
                Wt_lds[f + 0][wo] = wv.x;
                Wt_lds[f + 1][wo] = wv.y;
                Wt_lds[f + 2][wo] = wv.z;
                Wt_lds[f + 3][wo] = wv.w;
            }
        }
        __syncthreads();

        // compute: 64 f-steps, unrolled by 4
        #pragma unroll
        for (int f = 0; f < F_; f += 4) {
            float4 wf[4];
            #pragma unroll
            for (int k = 0; k < 4; ++k)
                wf[k] = *(const float4*)&Wt_lds[f + k][c0];
            #pragma unroll
            for (int i = 0; i < 8; ++i) {
                const float4 av = *(const float4*)&A_lds[trow * 8 + i][f];
                const float a0 = av.x, a1 = av.y, a2 = av.z, a3 = av.w;
                acc[i][0] += a0 * wf[0].x; acc[i][1] += a0 * wf[0].y;
                acc[i][2] += a0 * wf[0].z; acc[i][3] += a0 * wf[0].w;
                acc[i][0] += a1 * wf[1].x; acc[i][1] += a1 * wf[1].y;
                acc[i][2] += a1 * wf[1].z; acc[i][3] += a1 * wf[1].w;
                acc[i][0] += a2 * wf[2].x; acc[i][1] += a2 * wf[2].y;
                acc[i][2] += a2 * wf[2].z; acc[i][3] += a2 * wf[2].w;
                acc[i][0] += a3 * wf[3].x; acc[i][1] += a3 * wf[3].y;
                acc[i][2] += a3 * wf[3].z; acc[i][3] += a3 * wf[3].w;
            }
        }
    }

    // epilogue: ELU + row mask + store
    #pragma unroll
    for (int i = 0; i < 8; ++i) {
        const int m = m0 + trow * 8 + i;
        if (m < M_TOT) {
            const int n = m % N_;
            float v0 = acc[i][0], v1 = acc[i][1], v2 = acc[i][2], v3 = acc[i][3];
            v0 = v0 > 0.f ? v0 : expm1f(v0);
            v1 = v1 > 0.f ? v1 : expm1f(v1);
            v2 = v2 > 0.f ? v2 : expm1f(v2);
            v3 = v3 > 0.f ? v3 : expm1f(v3);
            if (n == N_ - 1) { v0 = v1 = v2 = v3 = 0.f; }
            *(float4*)(out + (size_t)m * OUT_ + c0) = make_float4(v0, v1, v2, v3);
        }
    }
}

extern "C" void kernel_launch(void* const* d_in, const int* in_sizes, int n_in,
                              void* d_out, int out_size, void* d_ws, size_t ws_size,
                              hipStream_t stream) {
    const float* x    = (const float*)d_in[0];
    const void*  adj  = d_in[1];
    const float* W    = (const float*)d_in[2];
    const float* bias = (const float*)d_in[3];
    float* out        = (float*)d_out;
    int*   flag       = (int*)d_ws;

    detect_idx_dtype<<<1, 256, 0, stream>>>((const int*)adj, flag);

    const int grid = (M_TOT + BM - 1) / BM;   // 2512 blocks
    spiral_conv_fp32<<<grid, THREADS, 0, stream>>>(x, adj, W, bias, out, flag);
}

// Round 2
// 111.582 us; speedup vs baseline: 3.0245x; 3.0245x over previous
//
#include <hip/hip_runtime.h>
#include <cstdint>
#include <cstddef>

// Problem constants
#define B_    32
#define N_    5023
#define F_    64
#define S_    9
#define OUT_  128
#define M_TOT (B_ * N_)        // 160736
#define K_    (S_ * F_)        // 576

// Workspace layout (bytes)
#define X_ELEMS   (B_ * N_ * F_)          // 10,287,104
#define WS_XB     0                        // bf16 x: 20,574,208 B
#define WS_WB     20574208                 // bf16 W: 147,456 B (16B aligned)
#define WS_IDX    20721664                 // int32 idx: 5,786,496 B
#define IDX_ELEMS (B_ * N_ * S_)           // 1,446,624
#define WS_FLAG   26508160

typedef __attribute__((ext_vector_type(8))) short    bf16x8;
typedef __attribute__((ext_vector_type(4))) float    f32x4;
typedef __attribute__((ext_vector_type(8))) unsigned short u16x8;

// ---------------------------------------------------------------------------
// adj dtype probe: int64 (odd 32-bit words all zero) vs int32.
// ---------------------------------------------------------------------------
__global__ void detect_idx_dtype(const int* __restrict__ adj_words,
                                 int* __restrict__ flag) {
    __shared__ int s_nz;
    if (threadIdx.x == 0) s_nz = 0;
    __syncthreads();
    int v = 0;
    for (int i = threadIdx.x; i < 4096; i += blockDim.x)
        v |= adj_words[2 * i + 1];
    if (v) atomicOr(&s_nz, 1);
    __syncthreads();
    if (threadIdx.x == 0) *flag = (s_nz == 0) ? 1 : 0;
}

// ---------------------------------------------------------------------------
// fp32 -> bf16 (RNE), 8 elems/thread
// ---------------------------------------------------------------------------
__global__ void cvt_f32_to_bf16(const float* __restrict__ in,
                                unsigned short* __restrict__ out, int n8) {
    const int i = blockIdx.x * blockDim.x + threadIdx.x;
    if (i >= n8) return;
    const float4* p = (const float4*)in + (size_t)i * 2;
    const float4 v0 = p[0], v1 = p[1];
    const float vv[8] = {v0.x, v0.y, v0.z, v0.w, v1.x, v1.y, v1.z, v1.w};
    u16x8 r;
    #pragma unroll
    for (int j = 0; j < 8; ++j) {
        uint32_t u = __float_as_uint(vv[j]);
        u = u + 0x7fffu + ((u >> 16) & 1u);
        r[j] = (unsigned short)(u >> 16);
    }
    *((u16x8*)out + i) = r;
}

// ---------------------------------------------------------------------------
// adj (int64 or int32) -> int32
// ---------------------------------------------------------------------------
__global__ void cvt_idx_i32(const void* __restrict__ adj, int* __restrict__ out,
                            const int* __restrict__ flag, int n) {
    const int i = blockIdx.x * blockDim.x + threadIdx.x;
    if (i >= n) return;
    if (*flag) out[i] = (int)((const long long*)adj)[i];
    else       out[i] = ((const int*)adj)[i];
}

// ---------------------------------------------------------------------------
// Main MFMA kernel: 128 rows x 128 cols per block, 4 waves (2x2), each wave
// 64x64 via 4x4 frags of mfma_f32_16x16x32_bf16. K-loop: 9 steps of 64.
// A-frags direct from global bf16-x (L2-resident batch slices).
// W staged per step via global_load_lds into XOR-swizzled double-buffered LDS.
// ---------------------------------------------------------------------------
__global__ __launch_bounds__(256, 2)
void spiral_mfma(const unsigned short* __restrict__ xb,
                 const int* __restrict__ adj,
                 const unsigned short* __restrict__ Wb,
                 const float* __restrict__ bias,
                 float* __restrict__ out) {
    __shared__ unsigned short Wlds[2][128 * 64];   // 2 x 16 KB

    const int tid = threadIdx.x;
    const int l   = tid & 63;
    const int w   = tid >> 6;
    const int wr  = w >> 1, wc = w & 1;

    // XCD-chunked bijective swizzle: grid 1256 = 8 * 157
    const int bid = blockIdx.x;
    const int nb  = (bid & 7) * 157 + (bid >> 3);
    const int m0  = nb * 128;

    // Per-mi row bases (A-frag rows: m = m0 + wr*64 + mi*16 + (l&15))
    int    adjb[4];
    size_t xrb[4];
    #pragma unroll
    for (int mi = 0; mi < 4; ++mi) {
        int m = m0 + wr * 64 + mi * 16 + (l & 15);
        if (m >= M_TOT) m = M_TOT - 1;
        adjb[mi] = m * S_;
        xrb[mi]  = (size_t)(m / N_) * (N_ * F_);
    }
    const int ko = (l >> 4) * 8;   // k element offset within a 32-k half

    f32x4 acc[4][4];
    #pragma unroll
    for (int mi = 0; mi < 4; ++mi)
        #pragma unroll
        for (int ni = 0; ni < 4; ++ni) {
            acc[mi][ni][0] = 0.f; acc[mi][ni][1] = 0.f;
            acc[mi][ni][2] = 0.f; acc[mi][ni][3] = 0.f;
        }

    // W staging: wave w stages rows [w*32, w*32+32), 4 issues x 8 rows.
    // LDS chunk swizzle: physical chunk p at row o holds logical chunk p^(o&7),
    // implemented by pre-swizzling the global source chunk.
    const int st_or = l >> 3;                 // row-within-8 for staging
    const int st_c  = (l & 7) ^ st_or;        // logical source chunk
    #define STAGE_W(s_, nb_)                                                        \
        do {                                                                        \
            const int rbase = w * 32;                                               \
            _Pragma("unroll")                                                       \
            for (int i_ = 0; i_ < 4; ++i_) {                                        \
                const int o_ = rbase + i_ * 8 + st_or;                              \
                const unsigned short* src_ = Wb + (size_t)o_ * K_ + (s_) * F_ + st_c * 8; \
                unsigned short* dst_ = &Wlds[nb_][(rbase + i_ * 8) * 64];           \
                __builtin_amdgcn_global_load_lds(                                   \
                    (const __attribute__((address_space(1))) void*)src_,            \
                    (__attribute__((address_space(3))) void*)dst_, 16, 0, 0);       \
            }                                                                       \
        } while (0)

    STAGE_W(0, 0);
    __syncthreads();

    for (int s = 0; s < S_; ++s) {
        const int cur = s & 1;
        if (s < S_ - 1) STAGE_W(s + 1, cur ^ 1);

        // A-frags: direct global loads (gathered rows, both k-halves)
        bf16x8 a[4][2];
        #pragma unroll
        for (int mi = 0; mi < 4; ++mi) {
            const int idx = adj[adjb[mi] + s];
            const unsigned short* p = xb + xrb[mi] + (size_t)idx * F_ + ko;
            a[mi][0] = *(const bf16x8*)p;
            a[mi][1] = *(const bf16x8*)(p + 32);
        }

        #pragma unroll
        for (int half = 0; half < 2; ++half) {
            bf16x8 bf[4];
            #pragma unroll
            for (int ni = 0; ni < 4; ++ni) {
                const int o = wc * 64 + ni * 16 + (l & 15);
                const int p = ((half << 2) + (l >> 4)) ^ (l & 7);   // phys chunk
                bf[ni] = *(const bf16x8*)&Wlds[cur][o * 64 + p * 8];
            }
            #pragma unroll
            for (int mi = 0; mi < 4; ++mi)
                #pragma unroll
                for (int ni = 0; ni < 4; ++ni)
                    acc[mi][ni] = __builtin_amdgcn_mfma_f32_16x16x32_bf16(
                        a[mi][half], bf[ni], acc[mi][ni], 0, 0, 0);
        }
        __syncthreads();
    }

    // Epilogue: bias + ELU + row-mask + direct stores.
    // C/D layout: col = l&15, row = (l>>4)*4 + j  (per 16x16 frag)
    float bias_n[4];
    #pragma unroll
    for (int ni = 0; ni < 4; ++ni)
        bias_n[ni] = bias[wc * 64 + ni * 16 + (l & 15)];

    const int rbase2 = m0 + wr * 64 + (l >> 4) * 4;
    const int colbase = wc * 64 + (l & 15);
    #pragma unroll
    for (int mi = 0; mi < 4; ++mi) {
        #pragma unroll
        for (int j = 0; j < 4; ++j) {
            const int m = rbase2 + mi * 16 + j;
            if (m < M_TOT) {
                const bool zero = ((m % N_) == (N_ - 1));
                float* orow = out + (size_t)m * OUT_ + colbase;
                #pragma unroll
                for (int ni = 0; ni < 4; ++ni) {
                    float v = acc[mi][ni][j] + bias_n[ni];
                    v = v > 0.f ? v : expm1f(v);
                    if (zero) v = 0.f;
                    orow[ni * 16] = v;
                }
            }
        }
    }
}

extern "C" void kernel_launch(void* const* d_in, const int* in_sizes, int n_in,
                              void* d_out, int out_size, void* d_ws, size_t ws_size,
                              hipStream_t stream) {
    const float* x    = (const float*)d_in[0];
    const void*  adj  = d_in[1];
    const float* W    = (const float*)d_in[2];
    const float* bias = (const float*)d_in[3];
    float* out        = (float*)d_out;

    char* ws = (char*)d_ws;
    unsigned short* xb  = (unsigned short*)(ws + WS_XB);
    unsigned short* Wb  = (unsigned short*)(ws + WS_WB);
    int*            ix  = (int*)(ws + WS_IDX);
    int*            flg = (int*)(ws + WS_FLAG);

    detect_idx_dtype<<<1, 256, 0, stream>>>((const int*)adj, flg);

    // conversions
    {
        const int n8 = X_ELEMS / 8;                 // 1,285,888
        cvt_f32_to_bf16<<<(n8 + 255) / 256, 256, 0, stream>>>(x, xb, n8);
    }
    {
        const int n8 = (OUT_ * K_) / 8;             // 9216
        cvt_f32_to_bf16<<<(n8 + 255) / 256, 256, 0, stream>>>(W, Wb, n8);
    }
    cvt_idx_i32<<<(IDX_ELEMS + 255) / 256, 256, 0, stream>>>(adj, ix, flg, IDX_ELEMS);

    const int grid = (M_TOT + 127) / 128;           // 1256 = 8 * 157
    spiral_mfma<<<grid, 256, 0, stream>>>(xb, ix, Wb, bias, out);
}

// Round 4
// 74.343 us; speedup vs baseline: 4.5395x; 1.5009x over previous
//
#include <hip/hip_runtime.h>
#include <cstdint>
#include <cstddef>

// Problem constants
#define B_    32
#define N_    5023
#define F_    64
#define S_    9
#define OUT_  128
#define M_TOT (B_ * N_)        // 160736
#define K_    (S_ * F_)        // 576

// Workspace layout (bytes)
#define X_ELEMS   (B_ * N_ * F_)          // 10,287,104
#define WS_XB     0                        // bf16 x: 20,574,208 B
#define WS_WB     20574208                 // bf16 W: 147,456 B
#define WS_IDX    20721664                 // int32 idx: 5,786,496 B
#define IDX_ELEMS (B_ * N_ * S_)           // 1,446,624

typedef __attribute__((ext_vector_type(8))) short          bf16x8;
typedef __attribute__((ext_vector_type(4))) float          f32x4;
typedef __attribute__((ext_vector_type(8))) unsigned short u16x8;

// ---------------------------------------------------------------------------
// Fused fp32->bf16 (RNE) conversion for x and W in one grid.
// ---------------------------------------------------------------------------
__global__ void cvt_xw(const float* __restrict__ x, const float* __restrict__ W,
                       unsigned short* __restrict__ xb, unsigned short* __restrict__ Wb,
                       int nx8, int nw8) {
    const int i = blockIdx.x * blockDim.x + threadIdx.x;
    const float* src;
    unsigned short* dst;
    if (i < nx8) { src = x + (size_t)i * 8; dst = xb + (size_t)i * 8; }
    else {
        const int j = i - nx8;
        if (j >= nw8) return;
        src = W + (size_t)j * 8; dst = Wb + (size_t)j * 8;
    }
    const float4 v0 = ((const float4*)src)[0], v1 = ((const float4*)src)[1];
    const float vv[8] = {v0.x, v0.y, v0.z, v0.w, v1.x, v1.y, v1.z, v1.w};
    u16x8 r;
    #pragma unroll
    for (int k = 0; k < 8; ++k) {
        uint32_t u = __float_as_uint(vv[k]);
        u = u + 0x7fffu + ((u >> 16) & 1u);
        r[k] = (unsigned short)(u >> 16);
    }
    *(u16x8*)dst = r;
}

// ---------------------------------------------------------------------------
// idx conversion with per-block dtype probe (int64 vs int32).
// ---------------------------------------------------------------------------
__global__ void cvt_idx(const void* __restrict__ adj, int* __restrict__ out, int n) {
    __shared__ int s_nz;
    const int t = threadIdx.x;
    if (t == 0) s_nz = 0;
    __syncthreads();
    if (((const int*)adj)[2 * t + 1] != 0) atomicOr(&s_nz, 1);
    __syncthreads();
    const bool is64 = (s_nz == 0);
    const int i0 = (blockIdx.x * blockDim.x + t) * 4;
    if (is64) {
        const long long* p = (const long long*)adj;
        #pragma unroll
        for (int k = 0; k < 4; ++k) { const int i = i0 + k; if (i < n) out[i] = (int)p[i]; }
    } else {
        const int* p = (const int*)adj;
        #pragma unroll
        for (int k = 0; k < 4; ++k) { const int i = i0 + k; if (i < n) out[i] = p[i]; }
    }
}

// ---------------------------------------------------------------------------
// Main MFMA kernel, barrier-free K-loop, explicit staging drain.
// Block: 256 rows x 64 cols, 8 waves (one 32x64 tile each, 2x4 frags of
// mfma_f32_16x16x32_bf16). Grid: 628 row-tiles x 2 col-tiles = 1256.
//
// W: ALL 9 K-slabs for this block's 64 cols staged once into LDS (73,728 B)
//    via global_load_lds, XOR-chunk-swizzled (phys16Bchunk = logical ^ (o&7))
//    by pre-swizzling the per-lane global source (LDS dest stays linear).
//    Handoff: explicit `s_waitcnt vmcnt(0)` + sched_barrier + ONE
//    __syncthreads(); ZERO barriers in the K-loop (waves drift freely).
// A: gathered direct from global bf16-x (L2-resident batch slices).
//    Pipeline: idx 2 steps ahead, A-frags 1 step ahead, fully unrolled.
// ---------------------------------------------------------------------------
__global__ __launch_bounds__(512, 4)
void spiral_mfma(const unsigned short* __restrict__ xb,
                 const int* __restrict__ adj,
                 const unsigned short* __restrict__ Wb,
                 const float* __restrict__ bias,
                 float* __restrict__ out) {
    __shared__ unsigned short Wlds[S_ * 64 * 64];   // 73,728 B

    const int tid = threadIdx.x;
    const int l   = tid & 63;
    const int w   = tid >> 6;                        // 0..7

    // XCD-chunked bijective swizzle (1256 = 8 * 157), col-tile fastest so
    // paired blocks (sharing A rows) land on the same XCD.
    const int bid  = blockIdx.x;
    const int nb   = (bid & 7) * 157 + (bid >> 3);
    const int rowT = nb >> 1, colT = nb & 1;
    const int m0   = rowT * 256;
    const int c0   = colT * 64;

    // A-gather bases: wave w owns rows [w*32, w*32+32)
    int    adjb[2];
    size_t xrb[2];
    #pragma unroll
    for (int mi = 0; mi < 2; ++mi) {
        int m = m0 + w * 32 + mi * 16 + (l & 15);
        if (m >= M_TOT) m = M_TOT - 1;
        adjb[mi] = m * S_;
        xrb[mi]  = (size_t)(m / N_) * (N_ * F_);
    }
    const int ko = (l >> 4) * 8;

    // idx for s=0,1 first (deepest dependent chain: idx -> A -> MFMA)
    int idq[2][2];
    #pragma unroll
    for (int mi = 0; mi < 2; ++mi) idq[0][mi] = adj[adjb[mi] + 0];
    #pragma unroll
    for (int mi = 0; mi < 2; ++mi) idq[1][mi] = adj[adjb[mi] + 1];

    // Stage all 9 W slabs: wave w covers rows [w*8, w*8+8) of each slab,
    // lane l -> row +(l>>3), phys chunk (l&7); source pre-swizzled so
    // phys chunk p at row o holds logical chunk p^(o&7).
    #pragma unroll
    for (int s = 0; s < S_; ++s) {
        const int o = w * 8 + (l >> 3);
        const unsigned short* src =
            Wb + (size_t)(c0 + o) * K_ + s * F_ + ((l & 7) ^ ((l >> 3) & 7)) * 8;
        unsigned short* dst = &Wlds[(s * 64 + w * 8) * 64];
        __builtin_amdgcn_global_load_lds(
            (const __attribute__((address_space(1))) void*)src,
            (__attribute__((address_space(3))) void*)dst, 16, 0, 0);
    }

    // A[0] prologue (depends on idq[0])
    bf16x8 a[2][2][2];
    #pragma unroll
    for (int mi = 0; mi < 2; ++mi) {
        const unsigned short* p = xb + xrb[mi] + (size_t)idq[0][mi] * F_ + ko;
        a[0][mi][0] = *(const bf16x8*)p;
        a[0][mi][1] = *(const bf16x8*)(p + 32);
    }

    // bias (epilogue data, loaded early to overlap)
    float bs[4];
    #pragma unroll
    for (int ni = 0; ni < 4; ++ni) bs[ni] = bias[c0 + ni * 16 + (l & 15)];

    f32x4 acc[2][4];
    #pragma unroll
    for (int mi = 0; mi < 2; ++mi)
        #pragma unroll
        for (int ni = 0; ni < 4; ++ni) {
            acc[mi][ni][0] = 0.f; acc[mi][ni][1] = 0.f;
            acc[mi][ni][2] = 0.f; acc[mi][ni][3] = 0.f;
        }

    // Handoff: explicit drain of this wave's LDS-DMA writes, then barrier.
    // (Do not rely on the compiler emitting vmcnt(0) at __syncthreads.)
    __builtin_amdgcn_sched_barrier(0);
    asm volatile("s_waitcnt vmcnt(0)" ::: "memory");
    __builtin_amdgcn_sched_barrier(0);
    __syncthreads();   // the ONLY barrier: all slabs complete

    #pragma unroll
    for (int s = 0; s < S_; ++s) {
        const int cur = s & 1, nxt = cur ^ 1;
        // idx 2 ahead (slot cur free: idx[s] consumed at step s-1)
        if (s < S_ - 2) {
            #pragma unroll
            for (int mi = 0; mi < 2; ++mi) idq[cur][mi] = adj[adjb[mi] + s + 2];
        }
        // A 1 ahead (uses idx[s+1], issued a full step ago)
        if (s < S_ - 1) {
            #pragma unroll
            for (int mi = 0; mi < 2; ++mi) {
                const unsigned short* p =
                    xb + xrb[mi] + (size_t)idq[nxt][mi] * F_ + ko;
                a[nxt][mi][0] = *(const bf16x8*)p;
                a[nxt][mi][1] = *(const bf16x8*)(p + 32);
            }
        }

        __builtin_amdgcn_s_setprio(1);
        #pragma unroll
        for (int h = 0; h < 2; ++h) {
            bf16x8 bf[4];
            #pragma unroll
            for (int ni = 0; ni < 4; ++ni) {
                const int o = ni * 16 + (l & 15);          // o&7 == l&7
                const int c = h * 4 + (l >> 4);            // logical chunk
                const int p = c ^ (l & 7);                 // phys chunk
                bf[ni] = *(const bf16x8*)&Wlds[(s * 64 + o) * 64 + p * 8];
            }
            #pragma unroll
            for (int mi = 0; mi < 2; ++mi)
                #pragma unroll
                for (int ni = 0; ni < 4; ++ni)
                    acc[mi][ni] = __builtin_amdgcn_mfma_f32_16x16x32_bf16(
                        a[cur][mi][h], bf[ni], acc[mi][ni], 0, 0, 0);
        }
        __builtin_amdgcn_s_setprio(0);
    }

    // Epilogue: bias + ELU + row-mask + stores.
    // C/D: col = l&15, row = (l>>4)*4 + j per 16x16 frag.
    const int rb = m0 + w * 32 + (l >> 4) * 4;
    const int cb = c0 + (l & 15);
    #pragma unroll
    for (int mi = 0; mi < 2; ++mi) {
        #pragma unroll
        for (int j = 0; j < 4; ++j) {
            const int m = rb + mi * 16 + j;
            if (m < M_TOT) {
                const bool z = ((m % N_) == (N_ - 1));
                float* orow = out + (size_t)m * OUT_ + cb;
                #pragma unroll
                for (int ni = 0; ni < 4; ++ni) {
                    float v = acc[mi][ni][j] + bs[ni];
                    v = v > 0.f ? v : expm1f(v);
                    if (z) v = 0.f;
                    orow[ni * 16] = v;
                }
            }
        }
    }
}

extern "C" void kernel_launch(void* const* d_in, const int* in_sizes, int n_in,
                              void* d_out, int out_size, void* d_ws, size_t ws_size,
                              hipStream_t stream) {
    const float* x    = (const float*)d_in[0];
    const void*  adj  = d_in[1];
    const float* W    = (const float*)d_in[2];
    const float* bias = (const float*)d_in[3];
    float* out        = (float*)d_out;

    char* ws = (char*)d_ws;
    unsigned short* xb = (unsigned short*)(ws + WS_XB);
    unsigned short* Wb = (unsigned short*)(ws + WS_WB);
    int*            ix = (int*)(ws + WS_IDX);

    const int nx8 = X_ELEMS / 8;          // 1,285,888
    const int nw8 = (OUT_ * K_) / 8;      // 9,216
    cvt_xw<<<(nx8 + nw8 + 255) / 256, 256, 0, stream>>>(x, W, xb, Wb, nx8, nw8);

    cvt_idx<<<(IDX_ELEMS / 4 + 255) / 256, 256, 0, stream>>>(adj, ix, IDX_ELEMS);

    spiral_mfma<<<1256, 512, 0, stream>>>(xb, ix, Wb, bias, out);
}